// Round 4
// baseline (541.959 us; speedup 1.0000x reference)
//
#include <hip/hip_runtime.h>

// StyleAttentionExtractor: B=16, C=512, H=W=64 (HW=4096), S=19, seg 256x256.
// out[b,s,:] = where(cnt>0, relu(maskedmean(x)) @ Ws[s]^T + bs[s], 0)

#define NB 16
#define NS 19
#define NC 512

// ---------------- K1: expand masks to float planes + count partials ---------
// nearest resize 256->64: src = 4*dst. Grid 16*19*4 = 1216 blocks, 256 thr.
// Block = (b, s, hchunk of 16 dst rows); wave handles one dst row per iter.
__global__ __launch_bounds__(256) void k1_mask(const float* __restrict__ seg,
                                               float* __restrict__ maskf,
                                               unsigned int* __restrict__ cnt_part) {
  int bid = blockIdx.x;            // (b*19+s)*4 + hc
  int hc = bid & 3;
  int bs = bid >> 2;               // b*NS+s
  int t = threadIdx.x, lane = t & 63, wv = t >> 6;
  const float* sp = seg + ((size_t)bs << 16);
  float* mp = maskf + ((size_t)bs << 12);
  unsigned int cnt = 0;
#pragma unroll
  for (int i = 0; i < 4; ++i) {
    int h = (hc << 4) + (i << 2) + wv;                 // dst row
    float v = sp[(size_t)(h << 2) * 256 + (lane << 2)]; // src[4h][4w]
    bool nz = (v != 0.0f);
    mp[(h << 6) + lane] = nz ? 1.0f : 0.0f;
    unsigned long long bal = __ballot(nz);
    cnt += (unsigned int)__popcll(bal);
  }
  if (lane == 0) cnt_part[(bs << 4) + (hc << 2) + wv] = cnt;
}

// ---------------- K2: masked segment sums, pure-fmac streaming pass ---------
// Grid 1024 = b(16) x cg(32) x half(2). Wave owns (b, 4 channels, 2048 hw).
// Per iter: 4 x-float4 + 19 independent mf-float4 loads -> 304 fmacs.
__global__ __launch_bounds__(256, 4) void k2_sums(const float* __restrict__ x,
                                                  const float* __restrict__ maskf,
                                                  float* __restrict__ sums) {
  int bid = blockIdx.x;
  int b = bid >> 6;
  int cg = (bid >> 1) & 31;
  int half = bid & 1;
  int wv = threadIdx.x >> 6, lane = threadIdx.x & 63;
  int ch0 = ((cg << 2) + wv) << 2;
  const float4* px0 = (const float4*)(x + ((size_t)(b * NC + ch0 + 0) << 12));
  const float4* px1 = (const float4*)(x + ((size_t)(b * NC + ch0 + 1) << 12));
  const float4* px2 = (const float4*)(x + ((size_t)(b * NC + ch0 + 2) << 12));
  const float4* px3 = (const float4*)(x + ((size_t)(b * NC + ch0 + 3) << 12));
  const float4* pmf = (const float4*)(maskf + ((size_t)(b * NS) << 12));
  int base = (half << 9) + lane;   // float4 units (plane = 1024 float4)

  float acc[4][NS];
#pragma unroll
  for (int ci = 0; ci < 4; ++ci)
#pragma unroll
    for (int s = 0; s < NS; ++s) acc[ci][s] = 0.0f;

  for (int it = 0; it < 8; ++it) {
    int idx = base + (it << 6);
    float4 xv0 = px0[idx];
    float4 xv1 = px1[idx];
    float4 xv2 = px2[idx];
    float4 xv3 = px3[idx];
#pragma unroll
    for (int s = 0; s < NS; ++s) {
      float4 mf = pmf[(s << 10) + idx];     // L2/L3-hot 5 MB total
      acc[0][s] += xv0.x * mf.x; acc[0][s] += xv0.y * mf.y; acc[0][s] += xv0.z * mf.z; acc[0][s] += xv0.w * mf.w;
      acc[1][s] += xv1.x * mf.x; acc[1][s] += xv1.y * mf.y; acc[1][s] += xv1.z * mf.z; acc[1][s] += xv1.w * mf.w;
      acc[2][s] += xv2.x * mf.x; acc[2][s] += xv2.y * mf.y; acc[2][s] += xv2.z * mf.z; acc[2][s] += xv2.w * mf.w;
      acc[3][s] += xv3.x * mf.x; acc[3][s] += xv3.y * mf.y; acc[3][s] += xv3.z * mf.z; acc[3][s] += xv3.w * mf.w;
    }
  }

  // cross-lane reduction + store partials: sums[half][b][s][c]
  float* sp = sums + (((size_t)half * NB + b) * NS) * (size_t)NC + ch0;
#pragma unroll
  for (int ci = 0; ci < 4; ++ci) {
#pragma unroll
    for (int s = 0; s < NS; ++s) {
      float v = acc[ci][s];
#pragma unroll
      for (int off = 32; off > 0; off >>= 1) v += __shfl_xor(v, off, 64);
      if (lane == 0) sp[(size_t)s * NC + ci] = v;
    }
  }
}

// ---------------- K3a: counts -> feat = relu(mean), zero-mask ---------------
// Block per (b,s). Writes feat[s][b][ci] + mask[s][b].
__global__ __launch_bounds__(256) void k3a_feat(const float* __restrict__ sums,
                                                const unsigned int* __restrict__ cnt_part,
                                                float* __restrict__ featbuf,
                                                float* __restrict__ maskv) {
  int bid = blockIdx.x;  // 304 = B*S
  int b = bid / NS, s = bid - b * NS;
  int t = threadIdx.x, lane = t & 63;

  unsigned int cp = (lane < 16) ? cnt_part[((b * NS + s) << 4) + lane] : 0u;
#pragma unroll
  for (int off = 32; off > 0; off >>= 1) cp += __shfl_xor(cp, off, 64);

  float* f = featbuf + ((size_t)s * NB + b) * NC;
  if (cp == 0u) {
    ((float2*)f)[t] = make_float2(0.0f, 0.0f);
    if (t == 0) maskv[s * NB + b] = 0.0f;
    return;
  }
  if (t == 0) maskv[s * NB + b] = 1.0f;
  float inv = 1.0f / (float)cp;
  const float* s0 = sums + (((size_t)0 * NB + b) * NS + s) * NC;
  const float* s1 = sums + (((size_t)1 * NB + b) * NS + s) * NC;
#pragma unroll
  for (int k = 0; k < 2; ++k) {
    int i = t + (k << 8);
    float v = (s0[i] + s1[i]) * inv;
    f[i] = v > 0.0f ? v : 0.0f;
  }
}

// ---------------- K3b: per-segment linear, Ws read exactly once -------------
// Grid 19*64 blocks; block stages feat[s] (16x512 = 32 KB) in LDS and owns a
// cotile of 8 c_out rows (2 per wave): Ws rows coalesced, read exactly once.
__global__ __launch_bounds__(256) void k3b_lin(const float* __restrict__ featbuf,
                                               const float* __restrict__ maskv,
                                               const float* __restrict__ Ws,
                                               const float* __restrict__ bsv,
                                               float* __restrict__ out) {
  __shared__ __align__(16) float feat[NB * NC];  // 32 KB
  int bid = blockIdx.x;          // 1216 = s(19) * cotile(64)
  int s = bid >> 6;
  int cot = (bid & 63) << 3;
  int t = threadIdx.x, lane = t & 63, wave = t >> 6;
  int coA = cot + wave, coB = cot + wave + 4;

  // issue Ws row loads first (read-once from HBM, longest latency)
  const float4* wrA = (const float4*)(Ws + ((size_t)s * NC + coA) * NC);
  const float4* wrB = (const float4*)(Ws + ((size_t)s * NC + coB) * NC);
  float4 wA0 = wrA[lane], wA1 = wrA[64 + lane];
  float4 wB0 = wrB[lane], wB1 = wrB[64 + lane];
  float biasA = bsv[s * NC + coA], biasB = bsv[s * NC + coB];

  // cooperative stage of feat[s]: 8192 floats = 2048 float4
  const float4* fsrc = (const float4*)(featbuf + (size_t)s * NB * NC);
  float4* fdst = (float4*)feat;
#pragma unroll
  for (int k = 0; k < 8; ++k) fdst[t + (k << 8)] = fsrc[t + (k << 8)];
  __syncthreads();

  const float4* fv = (const float4*)feat;
  float accA[NB], accB[NB];
#pragma unroll
  for (int b = 0; b < NB; ++b) {
    float4 f0 = fv[(b << 7) + lane];
    float4 f1 = fv[(b << 7) + 64 + lane];
    accA[b] = wA0.x * f0.x + wA0.y * f0.y + wA0.z * f0.z + wA0.w * f0.w +
              wA1.x * f1.x + wA1.y * f1.y + wA1.z * f1.z + wA1.w * f1.w;
    accB[b] = wB0.x * f0.x + wB0.y * f0.y + wB0.z * f0.z + wB0.w * f0.w +
              wB1.x * f1.x + wB1.y * f1.y + wB1.z * f1.z + wB1.w * f1.w;
  }
#pragma unroll
  for (int b = 0; b < NB; ++b) {
    float a = accA[b], c = accB[b];
#pragma unroll
    for (int off = 32; off > 0; off >>= 1) { a += __shfl_xor(a, off, 64); c += __shfl_xor(c, off, 64); }
    if (lane == 0) {
      float m = maskv[s * NB + b];
      out[((size_t)(b * NS + s)) * NC + coA] = (a + biasA) * m;
      out[((size_t)(b * NS + s)) * NC + coB] = (c + biasB) * m;
    }
  }
}

extern "C" void kernel_launch(void* const* d_in, const int* in_sizes, int n_in,
                              void* d_out, int out_size, void* d_ws, size_t ws_size,
                              hipStream_t stream) {
  const float* x   = (const float*)d_in[0];   // [16,512,64,64]
  const float* seg = (const float*)d_in[1];   // [16,19,256,256]
  const float* Ws  = (const float*)d_in[2];   // [19,512,512]
  const float* bsv = (const float*)d_in[3];   // [19,512]
  float* out = (float*)d_out;                 // [16,19,512]

  char* ws = (char*)d_ws;
  size_t off = 0;
  float*        maskf    = (float*)(ws + off); off += 4980736;   // 16*19*4096*4
  unsigned int* cnt_part = (unsigned int*)(ws + off); off += 19456;  // 16*19*16*4
  float*        sums     = (float*)(ws + off); off += 1245184;   // 2*16*19*512*4
  float*        featbuf  = (float*)(ws + off); off += 622592;    // 19*16*512*4
  float*        maskv    = (float*)(ws + off); off += 1216;      // 19*16*4
  // total ws use: ~6.9 MB

  k1_mask<<<NB * NS * 4, 256, 0, stream>>>(seg, maskf, cnt_part);
  k2_sums<<<1024, 256, 0, stream>>>(x, maskf, sums);
  k3a_feat<<<NB * NS, 256, 0, stream>>>(sums, cnt_part, featbuf, maskv);
  k3b_lin<<<NS * 64, 256, 0, stream>>>(featbuf, maskv, Ws, bsv, out);
}